// Round 4
// baseline (246.134 us; speedup 1.0000x reference)
//
#include <hip/hip_runtime.h>
#include <hip/hip_bf16.h>

#define BATCH 2
#define SEQLEN 2048
#define DMODEL 256
#define DINNER 512
#define NHEADS 8
#define HEADDIM 64
#define DSTATE 64
#define CONVDIM 640
#define DINPROJ 1160
#define NTOK (BATCH*SEQLEN)
#define Q 64
#define NCH (SEQLEN/Q)
#define TS 72          // chunk1 tile stride: word-stride 36 -> bank step 4, 2-way (free)
#define RS3 196        // conv slab stride
#define GS 536         // tail G stride: word-stride 268 -> bank step 12, 2-way (free)

typedef short v8s __attribute__((ext_vector_type(8)));
typedef float v4f __attribute__((ext_vector_type(4)));

__device__ __forceinline__ unsigned short f2bf(float f){
    __hip_bfloat16 h = __float2bfloat16(f);
    return *reinterpret_cast<unsigned short*>(&h);
}
__device__ __forceinline__ float bf2f(unsigned short u){
    unsigned int x = ((unsigned int)u) << 16;
    return __uint_as_float(x);
}

// ---------------- fused LN + in-proj GEMM (+res copy & Wout conversion in pad blocks) ----------------
// Each 64x64 tile block is self-contained: LN its 64 tokens from hid (fp32), gather-transpose its
// 64 W_in columns from fp32, both into XOR-chunk-swizzled LDS (read path identical to round-3).
__global__ __launch_bounds__(256) void k_fused_in(
        const float* __restrict__ hid, const float* __restrict__ nw, const float* __restrict__ nb,
        const float* __restrict__ Win, const float* __restrict__ Wout, const float* __restrict__ rms_w,
        float* __restrict__ res, unsigned short* __restrict__ zxb, unsigned short* __restrict__ Wto){
    int bx = blockIdx.x, by = blockIdx.y;
    int t = threadIdx.x;
    int tok0 = bx*64;
    if(by == 19){
        // all-padding tile: do res copy (64 tokens) + Wto conversion (4 columns)
        #pragma unroll
        for(int i=0;i<16;i++){
            int u = t + i*256;          // 4096 float4 chunks
            int row = u>>6, c4 = u&63;
            float4 v = *(const float4*)(hid + (size_t)(tok0+row)*DMODEL + c4*4);
            *(float4*)(res + (size_t)(tok0+row)*DMODEL + c4*4) = v;
        }
        int n  = bx*4 + (t>>6);
        int k0 = (t&63)*8;
        union { v8s v; unsigned short u[8]; } pk;
        #pragma unroll
        for(int m=0;m<8;m++){
            int k = k0+m;
            pk.u[m] = f2bf(Wout[(size_t)k*DMODEL + n] * rms_w[k]);
        }
        *(v8s*)&Wto[(size_t)n*DINNER + k0] = pk.v;
        return;
    }
    __shared__ __align__(16) unsigned short As[64*256];
    __shared__ __align__(16) unsigned short Bs[64*256];
    int n0 = by*64;
    // ---- A-side: LayerNorm 64 tokens; 4 threads per token, 64 ch each ----
    {
        int j = t>>2, p = t&3;
        const float* hp = hid + (size_t)(tok0+j)*DMODEL + p*64;
        float xv[64];
        float sum=0.f, sq=0.f;
        #pragma unroll
        for(int i=0;i<16;i++){
            float4 v = *(const float4*)(hp + i*4);
            xv[i*4+0]=v.x; xv[i*4+1]=v.y; xv[i*4+2]=v.z; xv[i*4+3]=v.w;
            sum += v.x+v.y+v.z+v.w;
            sq  += v.x*v.x + v.y*v.y + v.z*v.z + v.w*v.w;
        }
        sum += __shfl_xor(sum,1); sq += __shfl_xor(sq,1);
        sum += __shfl_xor(sum,2); sq += __shfl_xor(sq,2);
        float mu   = sum*(1.f/256.f);
        float var  = sq*(1.f/256.f) - mu*mu;
        float rstd = rsqrtf(var + 1e-5f);
        #pragma unroll
        for(int i=0;i<8;i++){
            union { v8s v; unsigned short u[8]; } pk;
            #pragma unroll
            for(int m=0;m<8;m++){
                int c  = i*8+m;
                int ch = p*64 + c;
                pk.u[m] = f2bf((xv[c]-mu)*rstd*nw[ch] + nb[ch]);
            }
            int chunk = p*8 + i;
            *(v8s*)&As[j*256 + ((chunk ^ (j&7)))*8] = pk.v;
        }
    }
    // ---- B-side: gather-transpose W_in columns (k-contiguous per thread, lane-coalesced over n) ----
    {
        int n_l = t&63, g = t>>6;
        int nglob = n0 + n_l;
        #pragma unroll
        for(int i=0;i<8;i++){
            int chunk = g*8 + i;
            union { v8s v; unsigned short u[8]; } pk;
            #pragma unroll
            for(int m=0;m<8;m++){
                int k = chunk*8 + m;
                float v = (nglob < DINPROJ) ? Win[(size_t)k*DINPROJ + nglob] : 0.f;
                pk.u[m] = f2bf(v);
            }
            *(v8s*)&Bs[n_l*256 + ((chunk ^ (n_l&7)))*8] = pk.v;
        }
    }
    __syncthreads();
    // ---- MFMA (identical read path to round-3) ----
    int lane = t & 63, w = t >> 6;
    int lanelow = lane & 15, quad = lane >> 4;
    int rw = (w & 1) * 32, cw = (w >> 1) * 32;
    v4f acc[2][2];
    #pragma unroll
    for(int mi=0;mi<2;mi++)
        #pragma unroll
        for(int ni=0;ni<2;ni++)
            acc[mi][ni] = (v4f){0.f,0.f,0.f,0.f};
    #pragma unroll
    for(int k0=0;k0<8;k0++){
        v8s a[2], b[2];
        #pragma unroll
        for(int mi=0;mi<2;mi++){
            int r = rw + mi*16 + lanelow;
            a[mi] = *(const v8s*)&As[r*256 + (((k0*4 + quad) ^ (r & 7)))*8];
        }
        #pragma unroll
        for(int ni=0;ni<2;ni++){
            int r = cw + ni*16 + lanelow;
            b[ni] = *(const v8s*)&Bs[r*256 + (((k0*4 + quad) ^ (r & 7)))*8];
        }
        #pragma unroll
        for(int mi=0;mi<2;mi++)
            #pragma unroll
            for(int ni=0;ni<2;ni++)
                acc[mi][ni] = __builtin_amdgcn_mfma_f32_16x16x32_bf16(a[mi], b[ni], acc[mi][ni], 0,0,0);
    }
    #pragma unroll
    for(int mi=0;mi<2;mi++){
        #pragma unroll
        for(int ni=0;ni<2;ni++){
            int col = n0 + cw + ni*16 + lanelow;
            if(col < DINPROJ){
                #pragma unroll
                for(int r=0;r<4;r++){
                    int row = tok0 + rw + mi*16 + quad*4 + r;
                    zxb[(size_t)row*DINPROJ + col] = f2bf(acc[mi][ni][r]);
                }
            }
        }
    }
}

// ---------------- fused conv + chunk-local SSD via MFMA; double-buffered slabs ----------------
__global__ __launch_bounds__(256) void k_chunk1(
        const unsigned short* __restrict__ zxb, const float* __restrict__ conv_w, const float* __restrict__ conv_b,
        const float* __restrict__ dt_bias, const float* __restrict__ A_log, const float* __restrict__ D_param,
        unsigned short* __restrict__ yw16, unsigned short* __restrict__ contrib16,
        float* __restrict__ Larr, float* __restrict__ decayArr, unsigned short* __restrict__ Ccv,
        unsigned int* __restrict__ bar){
    int blk = blockIdx.x;
    int c = blk & 31, h = (blk>>5)&7, b = blk>>8;
    int t = threadIdx.x;
    int lane = t & 63, w = t >> 6;
    int lanelow = lane & 15, quad = lane >> 4;
    if(blk==0 && t==0) *bar = 0u;   // reset grid barrier for k_tail2 (this dispatch completes first)
    __shared__ __align__(16) unsigned short Cb[64*TS];
    __shared__ __align__(16) unsigned short Bb[64*TS];
    __shared__ __align__(16) unsigned short BtW[64*TS];
    __shared__ __align__(16) unsigned short Xt[64*TS];
    __shared__ __align__(16) unsigned short BufRegion[2*19*RS3]; // 2 raw slabs; Gbuf aliases after conv
    __shared__ float Ls[Q], dts[Q], wch[Q];
    unsigned short* Gbuf = BufRegion;
    int l0 = c*Q;
    int bh = b*NHEADS + h;
    const unsigned short* zbase = zxb + (size_t)(b*SEQLEN + l0)*DINPROJ;

    // ---- stage slab 0 (rows l0-3 .. l0+15) ----
    {
        unsigned short* buf = BufRegion;
        #pragma unroll
        for(int i=0;i<4;i++){
            int u = t + 256*i;
            if(u < 19*48){
                int row = u/48, seg = u - row*48;
                int l = l0 - 3 + row;
                int gcol = (seg<16) ? (DINNER + h*HEADDIM + seg*4) : (2*DINNER + (seg-16)*4);
                ushort4 v;
                if(l >= 0) v = *(const ushort4*)(zxb + ((size_t)b*SEQLEN + l)*DINPROJ + gcol);
                else { v.x=0; v.y=0; v.z=0; v.w=0; }
                *(ushort4*)&buf[row*RS3 + seg*4] = v;
            }
        }
    }
    // ---- dt softplus + cumulative L scan + wch ----
    if(t < Q){
        float v = bf2f(zbase[(size_t)t*DINPROJ + (DINPROJ-NHEADS) + h]) + dt_bias[h];
        float dt = (v > 20.f) ? v : log1pf(__expf(v));
        float A  = -__expf(A_log[h]);
        float ld = dt*A;
        #pragma unroll
        for(int off=1; off<64; off<<=1){
            float u = __shfl_up(ld, off);
            if(lane >= off) ld += u;
        }
        Ls[t] = ld; dts[t] = dt;
        float l63 = __shfl(ld, 63);
        wch[t] = __expf(l63 - ld) * dt;
    }
    __syncthreads();

    unsigned short* CcP = Ccv + ((size_t)b*NCH + c)*4096;
    // ---- pipelined conv: load slab s+1 to regs (early), conv slab s, LDS-write slab s+1 (late) ----
    for(int s=0; s<4; s++){
        unsigned short* cur = BufRegion + (s&1)*(19*RS3);
        unsigned short* nxt = BufRegion + ((s+1)&1)*(19*RS3);
        ushort4 stg[4];
        if(s < 3){
            #pragma unroll
            for(int i=0;i<4;i++){
                int u = t + 256*i;
                if(u < 19*48){
                    int row = u/48, seg = u - row*48;
                    int l = l0 + (s+1)*16 - 3 + row;
                    int gcol = (seg<16) ? (DINNER + h*HEADDIM + seg*4) : (2*DINNER + (seg-16)*4);
                    stg[i] = *(const ushort4*)(zxb + ((size_t)b*SEQLEN + l)*DINPROJ + gcol);
                }
            }
        }
        #pragma unroll
        for(int i=0;i<3;i++){
            int u = t + 256*i;
            int stl = u & 15, grp = u >> 4;
            int st = s*16 + stl;
            int ch = grp*4;
            float xk[4][4];
            #pragma unroll
            for(int k=0;k<4;k++){
                ushort4 v = *(const ushort4*)&cur[(stl+k)*RS3 + ch];
                xk[k][0]=bf2f(v.x); xk[k][1]=bf2f(v.y); xk[k][2]=bf2f(v.z); xk[k][3]=bf2f(v.w);
            }
            float wst = wch[st];
            #pragma unroll
            for(int j=0;j<4;j++){
                int chj = ch+j;
                int cc = (chj<64) ? (h*HEADDIM + chj) : (448 + chj);
                float4 wv = *(const float4*)&conv_w[cc*4];
                float acc = conv_b[cc] + wv.x*xk[0][j] + wv.y*xk[1][j] + wv.z*xk[2][j] + wv.w*xk[3][j];
                float sv = acc/(1.f+__expf(-acc));
                if(chj < 64){
                    Xt[chj*TS + st] = f2bf(sv);
                } else if(chj < 128){
                    int n = chj-64;
                    Bb[st*TS + n]  = f2bf(sv);
                    BtW[n*TS + st] = f2bf(sv*wst);
                } else {
                    int n = chj-128;
                    unsigned short sb16 = f2bf(sv);
                    Cb[st*TS + n] = sb16;
                    if(h==0) CcP[st*64 + n] = sb16;
                }
            }
        }
        if(s < 3){
            #pragma unroll
            for(int i=0;i<4;i++){
                int u = t + 256*i;
                if(u < 19*48){
                    int row = u/48, seg = u - row*48;
                    *(ushort4*)&nxt[row*RS3 + seg*4] = stg[i];
                }
            }
        }
        __syncthreads();
    }
    // conv fully done: raw slabs dead, Gbuf may be written
    v4f g[4];
    #pragma unroll
    for(int nt=0;nt<4;nt++) g[nt] = (v4f){0.f,0.f,0.f,0.f};
    #pragma unroll
    for(int kk=0;kk<2;kk++){
        v8s a = *(const v8s*)&Cb[(w*16+lanelow)*TS + kk*32 + quad*8];
        #pragma unroll
        for(int nt=0;nt<4;nt++){
            v8s bb = *(const v8s*)&Bb[(nt*16+lanelow)*TS + kk*32 + quad*8];
            g[nt] = __builtin_amdgcn_mfma_f32_16x16x32_bf16(a, bb, g[nt], 0,0,0);
        }
    }
    float Lrow[4];
    #pragma unroll
    for(int r=0;r<4;r++) Lrow[r] = Ls[w*16 + quad*4 + r];
    #pragma unroll
    for(int nt=0;nt<4;nt++){
        int col = nt*16 + lanelow;
        float Lc = Ls[col], dtc = dts[col];
        #pragma unroll
        for(int r=0;r<4;r++){
            int rowg = w*16 + quad*4 + r;
            float val = (col <= rowg) ? g[nt][r] * __expf(Lrow[r]-Lc) * dtc : 0.f;
            Gbuf[rowg*TS + col] = f2bf(val);
        }
    }
    __syncthreads();
    v4f ya[4], sa[4];
    #pragma unroll
    for(int nt=0;nt<4;nt++){ ya[nt]=(v4f){0.f,0.f,0.f,0.f}; sa[nt]=(v4f){0.f,0.f,0.f,0.f}; }
    #pragma unroll
    for(int kk=0;kk<2;kk++){
        v8s ag = *(const v8s*)&Gbuf[(w*16+lanelow)*TS + kk*32 + quad*8];
        v8s ax = *(const v8s*)&Xt[(w*16+lanelow)*TS + kk*32 + quad*8];
        #pragma unroll
        for(int nt=0;nt<4;nt++){
            v8s bx = *(const v8s*)&Xt[(nt*16+lanelow)*TS + kk*32 + quad*8];
            v8s bw = *(const v8s*)&BtW[(nt*16+lanelow)*TS + kk*32 + quad*8];
            ya[nt] = __builtin_amdgcn_mfma_f32_16x16x32_bf16(ag, bx, ya[nt], 0,0,0);
            sa[nt] = __builtin_amdgcn_mfma_f32_16x16x32_bf16(ax, bw, sa[nt], 0,0,0);
        }
    }
    float Dp = D_param[h];
    #pragma unroll
    for(int nt=0;nt<4;nt++){
        int col = nt*16 + lanelow;
        #pragma unroll
        for(int r=0;r<4;r++){
            int i = w*16 + quad*4 + r;
            float xval = bf2f(Xt[col*TS + i]);
            yw16[((size_t)b*SEQLEN + l0 + i)*DINNER + h*HEADDIM + col] = f2bf(ya[nt][r] + Dp*xval);
            contrib16[(((size_t)bh*NCH + c)*64 + i)*64 + col] = f2bf(sa[nt][r]);
        }
    }
    if(t < Q) Larr[((size_t)bh*NCH + c)*Q + t] = Ls[t];
    if(t == 0) decayArr[bh*NCH + c] = __expf(Ls[Q-1]);
}

// ---------------- fused inter-chunk scan + y + gate + RMS + out-proj (grid barrier between phases) ----------------
__global__ __launch_bounds__(512) void k_tail2(
        const unsigned short* __restrict__ Ccv, unsigned short* __restrict__ Sb,
        const float* __restrict__ Larr, const unsigned short* __restrict__ yw16,
        const unsigned short* __restrict__ zxb, const unsigned short* __restrict__ Wto,
        const unsigned short* __restrict__ contrib16, const float* __restrict__ decayA,
        unsigned int* __restrict__ bar, float* __restrict__ out){
    int blk = blockIdx.x;
    int t = threadIdx.x;
    // ---- phase 1: inter-chunk state scan (identical mapping to old k_chunk2) ----
    if(t < 256){
        int bh2 = blk>>4, part = blk&15;
        size_t base = (size_t)bh2*NCH*4096 + part*256 + t;
        float vals[NCH];
        #pragma unroll
        for(int c2=0;c2<NCH;c2++) vals[c2] = bf2f(contrib16[base + (size_t)c2*4096]);
        float s0 = 0.f;
        #pragma unroll
        for(int c2=0;c2<NCH;c2++){
            Sb[base + (size_t)c2*4096] = f2bf(s0);
            s0 = fmaf(s0, decayA[bh2*NCH + c2], vals[c2]);
        }
    }
    // ---- grid barrier (all 256 blocks co-resident: 1 block/CU guaranteed) ----
    __threadfence();
    __syncthreads();
    if(t == 0){
        atomicAdd(bar, 1u);
        while(atomicAdd(bar, 0u) < 256u){ __builtin_amdgcn_s_sleep(8); }
        __threadfence();
    }
    __syncthreads();
    // ---- phase 2: tail ----
    int q4 = blk & 3, c = (blk>>2) & 31, b = blk >> 7;
    int h = t >> 6, lane = t & 63;
    int lanelow = lane & 15, quad = lane >> 4;
    int bh = b*NHEADS + h;
    __shared__ __align__(16) unsigned short Gs[16*GS];
    __shared__ float wsum[8][16];
    __shared__ float rstdS[16];
    const unsigned short* Cp = Ccv + ((size_t)b*NCH + c)*4096;
    const unsigned short* Sp = Sb + ((size_t)bh*NCH + c)*4096;
    int row0 = q4*16;
    v8s a0 = *(const v8s*)(Cp + (row0+lanelow)*64 + quad*8);
    v8s a1 = *(const v8s*)(Cp + (row0+lanelow)*64 + 32 + quad*8);
    v8s s[4][2];
    #pragma unroll
    for(int nt=0;nt<4;nt++){
        s[nt][0] = *(const v8s*)(Sp + (nt*16+lanelow)*64 + quad*8);
        s[nt][1] = *(const v8s*)(Sp + (nt*16+lanelow)*64 + 32 + quad*8);
    }
    float sq[4] = {0.f,0.f,0.f,0.f};
    const float* Lp = Larr + ((size_t)bh*NCH + c)*Q;
    float eL[4];
    #pragma unroll
    for(int r=0;r<4;r++) eL[r] = __expf(Lp[row0 + quad*4 + r]);
    size_t tok0 = (size_t)b*SEQLEN + c*Q + row0;
    #pragma unroll
    for(int nt=0;nt<4;nt++){
        v4f acc = (v4f){0.f,0.f,0.f,0.f};
        acc = __builtin_amdgcn_mfma_f32_16x16x32_bf16(a0, s[nt][0], acc, 0,0,0);
        acc = __builtin_amdgcn_mfma_f32_16x16x32_bf16(a1, s[nt][1], acc, 0,0,0);
        int col = h*HEADDIM + nt*16 + lanelow;
        #pragma unroll
        for(int r=0;r<4;r++){
            size_t tok = tok0 + quad*4 + r;
            float yv = acc[r]*eL[r] + bf2f(yw16[tok*DINNER + col]);
            float z  = bf2f(zxb[tok*DINPROJ + col]);
            float gg = yv * (z/(1.f+__expf(-z)));
            Gs[(quad*4+r)*GS + col] = f2bf(gg);
            sq[r] += gg*gg;
        }
    }
    #pragma unroll
    for(int r=0;r<4;r++){
        float v = sq[r];
        #pragma unroll
        for(int m=1;m<16;m<<=1) v += __shfl_xor(v, m);
        sq[r] = v;
    }
    if(lanelow==0){
        #pragma unroll
        for(int r=0;r<4;r++) wsum[h][quad*4 + r] = sq[r];
    }
    __syncthreads();
    if(t < 16){
        float tot = 0.f;
        #pragma unroll
        for(int hh=0;hh<8;hh++) tot += wsum[hh][t];
        rstdS[t] = rsqrtf(tot*(1.f/512.f) + 1e-5f);
    }
    __syncthreads();
    v4f acc2[2];
    #pragma unroll
    for(int nt=0;nt<2;nt++) acc2[nt] = (v4f){0.f,0.f,0.f,0.f};
    for(int ki=0; ki<16; ki++){
        v8s a = *(const v8s*)&Gs[lanelow*GS + ki*32 + quad*8];
        #pragma unroll
        for(int nt=0;nt<2;nt++){
            v8s bfr = *(const v8s*)(Wto + (size_t)(h*32 + nt*16 + lanelow)*DINNER + ki*32 + quad*8);
            acc2[nt] = __builtin_amdgcn_mfma_f32_16x16x32_bf16(a, bfr, acc2[nt], 0,0,0);
        }
    }
    float rs[4];
    #pragma unroll
    for(int r=0;r<4;r++) rs[r] = rstdS[quad*4 + r];
    #pragma unroll
    for(int nt=0;nt<2;nt++){
        int col = h*32 + nt*16 + lanelow;
        #pragma unroll
        for(int r=0;r<4;r++)
            out[(tok0 + quad*4 + r)*DMODEL + col] = acc2[nt][r]*rs[r];
    }
}

extern "C" void kernel_launch(void* const* d_in, const int* in_sizes, int n_in,
                              void* d_out, int out_size, void* d_ws, size_t ws_size,
                              hipStream_t stream) {
    const float* hid     = (const float*)d_in[0];
    const float* norm_w  = (const float*)d_in[1];
    const float* norm_b  = (const float*)d_in[2];
    const float* Win     = (const float*)d_in[3];
    const float* conv_w  = (const float*)d_in[4];
    const float* conv_b  = (const float*)d_in[5];
    const float* dt_bias = (const float*)d_in[6];
    const float* A_log   = (const float*)d_in[7];
    const float* D_param = (const float*)d_in[8];
    const float* rms_w   = (const float*)d_in[9];
    const float* Wout    = (const float*)d_in[10];

    unsigned short* contrib16 = (unsigned short*)d_ws;            // 16*32*4096 bf16
    float* Larr    = (float*)(contrib16 + (size_t)16*NCH*4096);   // 32768 f
    float* decayA  = Larr + (size_t)16*NCH*Q;                     // 512 f
    unsigned int* bar = (unsigned int*)(decayA + 512);            // 16 u32 (grid barrier)
    unsigned short* zxb  = (unsigned short*)(bar + 16);           // 4096*1160
    unsigned short* yw16 = zxb + (size_t)NTOK*DINPROJ;            // 4096*512
    unsigned short* Sb   = yw16 + (size_t)NTOK*DINNER;            // 16*32*4096
    unsigned short* Ccv  = Sb + (size_t)16*NCH*4096;              // 2*32*4096
    unsigned short* Wto  = Ccv + (size_t)BATCH*NCH*4096;          // 256*512

    float* out = (float*)d_out;
    float* res = out + (size_t)NTOK*DMODEL;

    k_fused_in<<<dim3(NTOK/64, 20), 256, 0, stream>>>(hid, norm_w, norm_b, Win, Wout, rms_w, res, zxb, Wto);
    k_chunk1<<<BATCH*NHEADS*NCH, 256, 0, stream>>>(zxb, conv_w, conv_b, dt_bias, A_log, D_param,
                                                   yw16, contrib16, Larr, decayA, Ccv, bar);
    k_tail2<<<BATCH*NCH*4, 512, 0, stream>>>(Ccv, Sb, Larr, yw16, zxb, Wto, contrib16, decayA, bar, out);
}

// Round 5
// 143.900 us; speedup vs baseline: 1.7105x; 1.7105x over previous
//
#include <hip/hip_runtime.h>
#include <hip/hip_bf16.h>

#define BATCH 2
#define SEQLEN 2048
#define DMODEL 256
#define DINNER 512
#define NHEADS 8
#define HEADDIM 64
#define DSTATE 64
#define CONVDIM 640
#define DINPROJ 1160
#define NTOK (BATCH*SEQLEN)
#define Q 64
#define NCH (SEQLEN/Q)
#define NPAD2 1280     // 10*128, zero-padded transposed W_in
#define TS 72          // chunk1 tile stride: word-stride 36 -> bank step 4, 2-way (free)
#define RS3 196        // conv slab stride
#define GS 536         // tail G stride: word-stride 268 -> bank step 12, 2-way (free)

typedef short v8s __attribute__((ext_vector_type(8)));
typedef float v4f __attribute__((ext_vector_type(4)));

__device__ __forceinline__ unsigned short f2bf(float f){
    __hip_bfloat16 h = __float2bfloat16(f);
    return *reinterpret_cast<unsigned short*>(&h);
}
__device__ __forceinline__ float bf2f(unsigned short u){
    unsigned int x = ((unsigned int)u) << 16;
    return __uint_as_float(x);
}
// async global->LDS DMA, 16B per lane; LDS dest = wave-uniform base + lane*16
__device__ __forceinline__ void gload_lds16(const unsigned short* g, unsigned short* l){
    __builtin_amdgcn_global_load_lds((const __attribute__((address_space(1))) void*)g,
                                     (__attribute__((address_space(3))) void*)l, 16, 0, 0);
}

// ---------------- prep: LayerNorm (+residual) and weight conversion, block-partitioned ----------------
// Wti branch rebuilt: 20 blocks LDS-transpose 64-column slices (coalesced reads, vector writes)
__global__ __launch_bounds__(256) void k_prep(
        const float* __restrict__ hid, const float* __restrict__ nw, const float* __restrict__ nb,
        const float* __restrict__ Win, const float* __restrict__ Wout, const float* __restrict__ rms_w,
        float* __restrict__ res, unsigned short* __restrict__ Xb,
        unsigned short* __restrict__ Wti, unsigned short* __restrict__ Wto){
    int bx = blockIdx.x;
    int t = threadIdx.x;
    __shared__ __align__(16) unsigned char shb[64*264*2];   // WT[64][264] ushort; LN uses 16KB of it
    if(bx < 256){
        float (*xs)[DMODEL] = (float(*)[DMODEL])shb;
        int tok0 = bx*16;
        for(int i=0;i<16;i++){
            int idx = i*256+t; int j = idx>>8, c = idx&255;
            float v = hid[(size_t)(tok0+j)*DMODEL + c];
            xs[j][c] = v;
            res[(size_t)(tok0+j)*DMODEL + c] = v;
        }
        __syncthreads();
        int g = t>>4, il = t&15;
        float sum=0.f, sumsq=0.f;
        for(int i=0;i<16;i++){ float v = xs[g][il*16+i]; sum += v; sumsq += v*v; }
        #pragma unroll
        for(int m=1;m<16;m<<=1){ sum += __shfl_xor(sum,m); sumsq += __shfl_xor(sumsq,m); }
        float mu   = sum*(1.f/256.f);
        float var  = sumsq*(1.f/256.f) - mu*mu;
        float rstd = rsqrtf(var + 1e-5f);
        for(int i=0;i<16;i++){
            int c = il*16+i;
            xs[g][c] = (xs[g][c]-mu)*rstd*nw[c] + nb[c];
        }
        __syncthreads();
        for(int i=0;i<16;i++){
            int idx = i*256+t; int j = idx>>8, c = idx&255;
            Xb[(size_t)(tok0+j)*DMODEL + c] = f2bf(xs[j][c]);
        }
    } else if(bx < 276){
        // Wti transpose via LDS: block handles cols n0..n0+63 over all 256 k-rows
        unsigned short (*WT)[264] = (unsigned short(*)[264])shb;
        int n0 = (bx-256)*64;
        int w = t>>6, lane = t&63;
        for(int it=0; it<64; it++){
            int k = it*4 + w;
            int n = n0 + lane;
            float v = (n < DINPROJ) ? Win[(size_t)k*DINPROJ + n] : 0.f;
            WT[lane][k] = f2bf(v);
        }
        __syncthreads();
        int n_l = t>>2, seg = t&3;
        int n = n0 + n_l;
        #pragma unroll
        for(int j=0;j<8;j++){
            *(v8s*)&Wti[(size_t)n*DMODEL + seg*64 + j*8] = *(const v8s*)&WT[n_l][seg*64 + j*8];
        }
    } else {
        int n0 = (bx - 276)*4;
        #pragma unroll
        for(int kk=0;kk<2;kk++){
            int k = t + kk*256;
            float rw = rms_w[k];
            #pragma unroll
            for(int i=0;i<4;i++){
                int n = n0+i;
                Wto[(size_t)n*DINNER + k] = f2bf(Wout[(size_t)k*DMODEL + n] * rw);
            }
        }
    }
}

// ---------------- in-proj MFMA GEMM: 64x64 tile, full-K one-shot DMA staging, 1 barrier ----------------
// LDS linear (DMA requirement) + XOR chunk swizzle on BOTH source and read (rule #21):
// LDS chunk (row,off) holds global chunk (row, off^(row&7)) -> 8 rows span all 32 banks on read.
__global__ __launch_bounds__(256) void k_gemm_in(
        const unsigned short* __restrict__ A, const unsigned short* __restrict__ Bt,
        unsigned short* __restrict__ zxb){
    __shared__ __align__(16) unsigned short As[64*256];
    __shared__ __align__(16) unsigned short Bs[64*256];
    int t = threadIdx.x;
    int lane = t & 63, w = t >> 6;
    int lanelow = lane & 15, quad = lane >> 4;
    int tok0 = blockIdx.x * 64;
    int n0   = blockIdx.y * 64;
    int rw = (w & 1) * 32, cw = (w >> 1) * 32;
    #pragma unroll
    for(int k=0;k<8;k++){
        int u = t + k*256;
        int row = u >> 5, off = u & 31;
        int soff = off ^ (row & 7);
        gload_lds16(A  + (size_t)(tok0+row)*DMODEL + soff*8, &As[(w*64 + k*256)*8]);
        gload_lds16(Bt + (size_t)(n0 +row)*DMODEL + soff*8, &Bs[(w*64 + k*256)*8]);
    }
    __syncthreads();
    v4f acc[2][2];
    #pragma unroll
    for(int mi=0;mi<2;mi++)
        #pragma unroll
        for(int ni=0;ni<2;ni++)
            acc[mi][ni] = (v4f){0.f,0.f,0.f,0.f};
    #pragma unroll
    for(int k0=0;k0<8;k0++){
        v8s a[2], b[2];
        #pragma unroll
        for(int mi=0;mi<2;mi++){
            int r = rw + mi*16 + lanelow;
            a[mi] = *(const v8s*)&As[r*256 + (((k0*4 + quad) ^ (r & 7)))*8];
        }
        #pragma unroll
        for(int ni=0;ni<2;ni++){
            int r = cw + ni*16 + lanelow;
            b[ni] = *(const v8s*)&Bs[r*256 + (((k0*4 + quad) ^ (r & 7)))*8];
        }
        #pragma unroll
        for(int mi=0;mi<2;mi++)
            #pragma unroll
            for(int ni=0;ni<2;ni++)
                acc[mi][ni] = __builtin_amdgcn_mfma_f32_16x16x32_bf16(a[mi], b[ni], acc[mi][ni], 0,0,0);
    }
    #pragma unroll
    for(int mi=0;mi<2;mi++){
        #pragma unroll
        for(int ni=0;ni<2;ni++){
            int col = n0 + cw + ni*16 + lanelow;
            if(col < DINPROJ){
                #pragma unroll
                for(int r=0;r<4;r++){
                    int row = tok0 + rw + mi*16 + quad*4 + r;
                    zxb[(size_t)row*DINPROJ + col] = f2bf(acc[mi][ni][r]);
                }
            }
        }
    }
}

// ---------------- fused conv + chunk-local SSD via MFMA; double-buffered slabs, 3 blocks/CU ----------------
__global__ __launch_bounds__(256) void k_chunk1(
        const unsigned short* __restrict__ zxb, const float* __restrict__ conv_w, const float* __restrict__ conv_b,
        const float* __restrict__ dt_bias, const float* __restrict__ A_log, const float* __restrict__ D_param,
        unsigned short* __restrict__ yw16, unsigned short* __restrict__ contrib16,
        float* __restrict__ Larr, float* __restrict__ decayArr, unsigned short* __restrict__ Ccv){
    int blk = blockIdx.x;
    int c = blk & 31, h = (blk>>5)&7, b = blk>>8;
    int t = threadIdx.x;
    int lane = t & 63, w = t >> 6;
    int lanelow = lane & 15, quad = lane >> 4;
    __shared__ __align__(16) unsigned short Cb[64*TS];
    __shared__ __align__(16) unsigned short Bb[64*TS];
    __shared__ __align__(16) unsigned short BtW[64*TS];
    __shared__ __align__(16) unsigned short Xt[64*TS];
    __shared__ __align__(16) unsigned short BufRegion[2*19*RS3]; // 2 raw slabs; Gbuf aliases after conv
    __shared__ float Ls[Q], dts[Q], wch[Q];
    unsigned short* Gbuf = BufRegion;
    int l0 = c*Q;
    int bh = b*NHEADS + h;
    const unsigned short* zbase = zxb + (size_t)(b*SEQLEN + l0)*DINPROJ;

    // ---- stage slab 0 (rows l0-3 .. l0+15) ----
    {
        unsigned short* buf = BufRegion;
        #pragma unroll
        for(int i=0;i<4;i++){
            int u = t + 256*i;
            if(u < 19*48){
                int row = u/48, seg = u - row*48;
                int l = l0 - 3 + row;
                int gcol = (seg<16) ? (DINNER + h*HEADDIM + seg*4) : (2*DINNER + (seg-16)*4);
                ushort4 v;
                if(l >= 0) v = *(const ushort4*)(zxb + ((size_t)b*SEQLEN + l)*DINPROJ + gcol);
                else { v.x=0; v.y=0; v.z=0; v.w=0; }
                *(ushort4*)&buf[row*RS3 + seg*4] = v;
            }
        }
    }
    // ---- dt softplus + cumulative L scan + wch ----
    if(t < Q){
        float v = bf2f(zbase[(size_t)t*DINPROJ + (DINPROJ-NHEADS) + h]) + dt_bias[h];
        float dt = (v > 20.f) ? v : log1pf(__expf(v));
        float A  = -__expf(A_log[h]);
        float ld = dt*A;
        #pragma unroll
        for(int off=1; off<64; off<<=1){
            float u = __shfl_up(ld, off);
            if(lane >= off) ld += u;
        }
        Ls[t] = ld; dts[t] = dt;
        float l63 = __shfl(ld, 63);
        wch[t] = __expf(l63 - ld) * dt;
    }
    __syncthreads();

    unsigned short* CcP = Ccv + ((size_t)b*NCH + c)*4096;
    // ---- pipelined conv: load slab s+1 to regs (early), conv slab s, LDS-write slab s+1 (late) ----
    for(int s=0; s<4; s++){
        unsigned short* cur = BufRegion + (s&1)*(19*RS3);
        unsigned short* nxt = BufRegion + ((s+1)&1)*(19*RS3);
        ushort4 stg[4];
        if(s < 3){
            #pragma unroll
            for(int i=0;i<4;i++){
                int u = t + 256*i;
                if(u < 19*48){
                    int row = u/48, seg = u - row*48;
                    int l = l0 + (s+1)*16 - 3 + row;
                    int gcol = (seg<16) ? (DINNER + h*HEADDIM + seg*4) : (2*DINNER + (seg-16)*4);
                    stg[i] = *(const ushort4*)(zxb + ((size_t)b*SEQLEN + l)*DINPROJ + gcol);
                }
            }
        }
        #pragma unroll
        for(int i=0;i<3;i++){
            int u = t + 256*i;
            int stl = u & 15, grp = u >> 4;
            int st = s*16 + stl;
            int ch = grp*4;
            float xk[4][4];
            #pragma unroll
            for(int k=0;k<4;k++){
                ushort4 v = *(const ushort4*)&cur[(stl+k)*RS3 + ch];
                xk[k][0]=bf2f(v.x); xk[k][1]=bf2f(v.y); xk[k][2]=bf2f(v.z); xk[k][3]=bf2f(v.w);
            }
            float wst = wch[st];
            #pragma unroll
            for(int j=0;j<4;j++){
                int chj = ch+j;
                int cc = (chj<64) ? (h*HEADDIM + chj) : (448 + chj);
                float4 wv = *(const float4*)&conv_w[cc*4];
                float acc = conv_b[cc] + wv.x*xk[0][j] + wv.y*xk[1][j] + wv.z*xk[2][j] + wv.w*xk[3][j];
                float sv = acc/(1.f+__expf(-acc));
                if(chj < 64){
                    Xt[chj*TS + st] = f2bf(sv);
                } else if(chj < 128){
                    int n = chj-64;
                    Bb[st*TS + n]  = f2bf(sv);
                    BtW[n*TS + st] = f2bf(sv*wst);
                } else {
                    int n = chj-128;
                    unsigned short sb16 = f2bf(sv);
                    Cb[st*TS + n] = sb16;
                    if(h==0) CcP[st*64 + n] = sb16;
                }
            }
        }
        if(s < 3){
            #pragma unroll
            for(int i=0;i<4;i++){
                int u = t + 256*i;
                if(u < 19*48){
                    int row = u/48, seg = u - row*48;
                    *(ushort4*)&nxt[row*RS3 + seg*4] = stg[i];
                }
            }
        }
        __syncthreads();
    }
    // conv fully done: raw slabs dead, Gbuf may be written
    v4f g[4];
    #pragma unroll
    for(int nt=0;nt<4;nt++) g[nt] = (v4f){0.f,0.f,0.f,0.f};
    #pragma unroll
    for(int kk=0;kk<2;kk++){
        v8s a = *(const v8s*)&Cb[(w*16+lanelow)*TS + kk*32 + quad*8];
        #pragma unroll
        for(int nt=0;nt<4;nt++){
            v8s bb = *(const v8s*)&Bb[(nt*16+lanelow)*TS + kk*32 + quad*8];
            g[nt] = __builtin_amdgcn_mfma_f32_16x16x32_bf16(a, bb, g[nt], 0,0,0);
        }
    }
    float Lrow[4];
    #pragma unroll
    for(int r=0;r<4;r++) Lrow[r] = Ls[w*16 + quad*4 + r];
    #pragma unroll
    for(int nt=0;nt<4;nt++){
        int col = nt*16 + lanelow;
        float Lc = Ls[col], dtc = dts[col];
        #pragma unroll
        for(int r=0;r<4;r++){
            int rowg = w*16 + quad*4 + r;
            float val = (col <= rowg) ? g[nt][r] * __expf(Lrow[r]-Lc) * dtc : 0.f;
            Gbuf[rowg*TS + col] = f2bf(val);
        }
    }
    __syncthreads();
    v4f ya[4], sa[4];
    #pragma unroll
    for(int nt=0;nt<4;nt++){ ya[nt]=(v4f){0.f,0.f,0.f,0.f}; sa[nt]=(v4f){0.f,0.f,0.f,0.f}; }
    #pragma unroll
    for(int kk=0;kk<2;kk++){
        v8s ag = *(const v8s*)&Gbuf[(w*16+lanelow)*TS + kk*32 + quad*8];
        v8s ax = *(const v8s*)&Xt[(w*16+lanelow)*TS + kk*32 + quad*8];
        #pragma unroll
        for(int nt=0;nt<4;nt++){
            v8s bx = *(const v8s*)&Xt[(nt*16+lanelow)*TS + kk*32 + quad*8];
            v8s bw = *(const v8s*)&BtW[(nt*16+lanelow)*TS + kk*32 + quad*8];
            ya[nt] = __builtin_amdgcn_mfma_f32_16x16x32_bf16(ag, bx, ya[nt], 0,0,0);
            sa[nt] = __builtin_amdgcn_mfma_f32_16x16x32_bf16(ax, bw, sa[nt], 0,0,0);
        }
    }
    float Dp = D_param[h];
    #pragma unroll
    for(int nt=0;nt<4;nt++){
        int col = nt*16 + lanelow;
        #pragma unroll
        for(int r=0;r<4;r++){
            int i = w*16 + quad*4 + r;
            float xval = bf2f(Xt[col*TS + i]);
            yw16[((size_t)b*SEQLEN + l0 + i)*DINNER + h*HEADDIM + col] = f2bf(ya[nt][r] + Dp*xval);
            contrib16[(((size_t)bh*NCH + c)*64 + i)*64 + col] = f2bf(sa[nt][r]);
        }
    }
    if(t < Q) Larr[((size_t)bh*NCH + c)*Q + t] = Ls[t];
    if(t == 0) decayArr[bh*NCH + c] = __expf(Ls[Q-1]);
}

// ---------------- inter-chunk state scan (bf16 in/out, fp32 accumulate) ----------------
__global__ __launch_bounds__(256) void k_chunk2(const unsigned short* __restrict__ contrib16,
                                                const float* __restrict__ decayArr,
                                                unsigned short* __restrict__ Sb){
    int bh = blockIdx.x >> 4;
    int part = blockIdx.x & 15;
    int e = part*256 + threadIdx.x;
    const size_t base = (size_t)bh*NCH*4096 + e;
    float vals[NCH];
    #pragma unroll
    for(int c=0;c<NCH;c++) vals[c] = bf2f(contrib16[base + (size_t)c*4096]);
    float s = 0.f;
    #pragma unroll
    for(int c=0;c<NCH;c++){
        Sb[base + (size_t)c*4096] = f2bf(s);
        s = fmaf(s, decayArr[bh*NCH + c], vals[c]);
    }
}

// ---------------- fused inter-chunk y + gate + RMS + out-proj -> fp32 out ----------------
// latency fixes: batched up-front yw16/zxb loads; register double-buffered Wto in ki-loop
__global__ __launch_bounds__(512) void k_tail(
        const unsigned short* __restrict__ Ccv, const unsigned short* __restrict__ Sb,
        const float* __restrict__ Larr, const unsigned short* __restrict__ yw16,
        const unsigned short* __restrict__ zxb, const unsigned short* __restrict__ Wto,
        float* __restrict__ out){
    int blk = blockIdx.x;
    int q4 = blk & 3, c = (blk>>2) & 31, b = blk >> 7;
    int t = threadIdx.x;
    int h = t >> 6, lane = t & 63;
    int lanelow = lane & 15, quad = lane >> 4;
    int bh = b*NHEADS + h;
    __shared__ __align__(16) unsigned short Gs[16*GS];
    __shared__ float wsum[8][16];
    __shared__ float rstdS[16];
    const unsigned short* Cp = Ccv + ((size_t)b*NCH + c)*4096;
    const unsigned short* Sp = Sb + ((size_t)bh*NCH + c)*4096;
    int row0 = q4*16;
    v8s a0 = *(const v8s*)(Cp + (row0+lanelow)*64 + quad*8);
    v8s a1 = *(const v8s*)(Cp + (row0+lanelow)*64 + 32 + quad*8);
    v8s s[4][2];
    #pragma unroll
    for(int nt=0;nt<4;nt++){
        s[nt][0] = *(const v8s*)(Sp + (nt*16+lanelow)*64 + quad*8);
        s[nt][1] = *(const v8s*)(Sp + (nt*16+lanelow)*64 + 32 + quad*8);
    }
    size_t tok0 = (size_t)b*SEQLEN + c*Q + row0;
    // batched independent loads: all yw16/zxb values + Lp, one latency exposure
    unsigned short ywr[4][4], zr[4][4];
    #pragma unroll
    for(int nt=0;nt<4;nt++){
        int col = h*HEADDIM + nt*16 + lanelow;
        #pragma unroll
        for(int r=0;r<4;r++){
            size_t tok = tok0 + quad*4 + r;
            ywr[nt][r] = yw16[tok*DINNER + col];
            zr[nt][r]  = zxb[tok*DINPROJ + col];
        }
    }
    const float* Lp = Larr + ((size_t)bh*NCH + c)*Q;
    float eL[4];
    #pragma unroll
    for(int r=0;r<4;r++) eL[r] = __expf(Lp[row0 + quad*4 + r]);
    // prefetch first Wto pair (hidden under the reduce barriers below)
    const unsigned short* WtoP = Wto + (size_t)(h*32 + lanelow)*DINNER + quad*8;
    v8s w0 = *(const v8s*)(WtoP);
    v8s w1 = *(const v8s*)(WtoP + (size_t)16*DINNER);
    float sq[4] = {0.f,0.f,0.f,0.f};
    #pragma unroll
    for(int nt=0;nt<4;nt++){
        v4f acc = (v4f){0.f,0.f,0.f,0.f};
        acc = __builtin_amdgcn_mfma_f32_16x16x32_bf16(a0, s[nt][0], acc, 0,0,0);
        acc = __builtin_amdgcn_mfma_f32_16x16x32_bf16(a1, s[nt][1], acc, 0,0,0);
        int col = h*HEADDIM + nt*16 + lanelow;
        #pragma unroll
        for(int r=0;r<4;r++){
            float yv = acc[r]*eL[r] + bf2f(ywr[nt][r]);
            float z  = bf2f(zr[nt][r]);
            float gg = yv * (z/(1.f+__expf(-z)));
            Gs[(quad*4+r)*GS + col] = f2bf(gg);
            sq[r] += gg*gg;
        }
    }
    #pragma unroll
    for(int r=0;r<4;r++){
        float v = sq[r];
        #pragma unroll
        for(int m=1;m<16;m<<=1) v += __shfl_xor(v, m);
        sq[r] = v;
    }
    if(lanelow==0){
        #pragma unroll
        for(int r=0;r<4;r++) wsum[h][quad*4 + r] = sq[r];
    }
    __syncthreads();
    if(t < 16){
        float tot = 0.f;
        #pragma unroll
        for(int hh=0;hh<8;hh++) tot += wsum[hh][t];
        rstdS[t] = rsqrtf(tot*(1.f/512.f) + 1e-5f);
    }
    __syncthreads();
    // out-proj: wave h computes cols [h*32, h*32+32); K=512; Wto double-buffered in regs
    v4f acc2[2];
    #pragma unroll
    for(int nt=0;nt<2;nt++) acc2[nt] = (v4f){0.f,0.f,0.f,0.f};
    #pragma unroll
    for(int ki=0; ki<16; ki++){
        v8s nw0, nw1;
        if(ki < 15){
            nw0 = *(const v8s*)(WtoP + (ki+1)*32);
            nw1 = *(const v8s*)(WtoP + (size_t)16*DINNER + (ki+1)*32);
        }
        v8s a = *(const v8s*)&Gs[lanelow*GS + ki*32 + quad*8];
        acc2[0] = __builtin_amdgcn_mfma_f32_16x16x32_bf16(a, w0, acc2[0], 0,0,0);
        acc2[1] = __builtin_amdgcn_mfma_f32_16x16x32_bf16(a, w1, acc2[1], 0,0,0);
        if(ki < 15){ w0 = nw0; w1 = nw1; }
    }
    float rs[4];
    #pragma unroll
    for(int r=0;r<4;r++) rs[r] = rstdS[quad*4 + r];
    #pragma unroll
    for(int nt=0;nt<2;nt++){
        int col = h*32 + nt*16 + lanelow;
        #pragma unroll
        for(int r=0;r<4;r++)
            out[(tok0 + quad*4 + r)*DMODEL + col] = acc2[nt][r]*rs[r];
    }
}

extern "C" void kernel_launch(void* const* d_in, const int* in_sizes, int n_in,
                              void* d_out, int out_size, void* d_ws, size_t ws_size,
                              hipStream_t stream) {
    const float* hid     = (const float*)d_in[0];
    const float* norm_w  = (const float*)d_in[1];
    const float* norm_b  = (const float*)d_in[2];
    const float* Win     = (const float*)d_in[3];
    const float* conv_w  = (const float*)d_in[4];
    const float* conv_b  = (const float*)d_in[5];
    const float* dt_bias = (const float*)d_in[6];
    const float* A_log   = (const float*)d_in[7];
    const float* D_param = (const float*)d_in[8];
    const float* rms_w   = (const float*)d_in[9];
    const float* Wout    = (const float*)d_in[10];

    unsigned short* contrib16 = (unsigned short*)d_ws;            // 16*32*4096 bf16
    float* Larr    = (float*)(contrib16 + (size_t)16*NCH*4096);   // 32768 f
    float* decayA  = Larr + (size_t)16*NCH*Q;                     // 512 f
    unsigned short* zxb  = (unsigned short*)(decayA + 512);       // 4096*1160
    unsigned short* yw16 = zxb + (size_t)NTOK*DINPROJ;            // 4096*512
    unsigned short* Sb   = yw16 + (size_t)NTOK*DINNER;            // 16*32*4096
    unsigned short* Ccv  = Sb + (size_t)16*NCH*4096;              // 2*32*4096
    unsigned short* Xb   = Ccv + (size_t)BATCH*NCH*4096;          // 4096*256
    unsigned short* Wti  = Xb + (size_t)NTOK*DMODEL;              // 1280*256
    unsigned short* Wto  = Wti + (size_t)NPAD2*DMODEL;            // 256*512

    float* out = (float*)d_out;
    float* res = out + (size_t)NTOK*DMODEL;

    k_prep<<<340, 256, 0, stream>>>(hid, norm_w, norm_b, Win, Wout, rms_w, res, Xb, Wti, Wto);
    k_gemm_in<<<dim3(NTOK/64, NPAD2/64), 256, 0, stream>>>(Xb, Wti, zxb);
    k_chunk1<<<BATCH*NHEADS*NCH, 256, 0, stream>>>(zxb, conv_w, conv_b, dt_bias, A_log, D_param,
                                                   yw16, contrib16, Larr, decayA, Ccv);
    k_chunk2<<<256, 256, 0, stream>>>(contrib16, decayA, Sb);
    k_tail<<<BATCH*NCH*4, 512, 0, stream>>>(Ccv, Sb, Larr, yw16, zxb, Wto, out);
}

// Round 6
// 126.077 us; speedup vs baseline: 1.9523x; 1.1414x over previous
//
#include <hip/hip_runtime.h>
#include <hip/hip_bf16.h>

#define BATCH 2
#define SEQLEN 2048
#define DMODEL 256
#define DINNER 512
#define NHEADS 8
#define HEADDIM 64
#define DSTATE 64
#define CONVDIM 640
#define DINPROJ 1160
#define NTOK (BATCH*SEQLEN)
#define Q 64
#define NCH (SEQLEN/Q)
#define NPAD2 1280     // 10*128, zero-padded transposed W_in
#define TS 72          // chunk1 tile stride: word-stride 36 -> bank step 4, 2-way (free)
#define RS3 196        // conv slab stride
#define GS 536         // tail G stride: word-stride 268 -> bank step 12, 2-way (free)

typedef short v8s __attribute__((ext_vector_type(8)));
typedef float v4f __attribute__((ext_vector_type(4)));

__device__ __forceinline__ unsigned short f2bf(float f){
    __hip_bfloat16 h = __float2bfloat16(f);
    return *reinterpret_cast<unsigned short*>(&h);
}
__device__ __forceinline__ float bf2f(unsigned short u){
    unsigned int x = ((unsigned int)u) << 16;
    return __uint_as_float(x);
}
// async global->LDS DMA, 16B per lane; LDS dest = wave-uniform base + lane*16
__device__ __forceinline__ void gload_lds16(const unsigned short* g, unsigned short* l){
    __builtin_amdgcn_global_load_lds((const __attribute__((address_space(1))) void*)g,
                                     (__attribute__((address_space(3))) void*)l, 16, 0, 0);
}

// ---------------- prep: LayerNorm (+residual) and weight conversion, block-partitioned ----------------
__global__ __launch_bounds__(256) void k_prep(
        const float* __restrict__ hid, const float* __restrict__ nw, const float* __restrict__ nb,
        const float* __restrict__ Win, const float* __restrict__ Wout, const float* __restrict__ rms_w,
        float* __restrict__ res, unsigned short* __restrict__ Xb,
        unsigned short* __restrict__ Wti, unsigned short* __restrict__ Wto){
    int bx = blockIdx.x;
    int t = threadIdx.x;
    if(bx < 256){
        __shared__ float xs[16][DMODEL];
        int tok0 = bx*16;
        for(int i=0;i<16;i++){
            int idx = i*256+t; int j = idx>>8, c = idx&255;
            float v = hid[(size_t)(tok0+j)*DMODEL + c];
            xs[j][c] = v;
            res[(size_t)(tok0+j)*DMODEL + c] = v;
        }
        __syncthreads();
        int g = t>>4, il = t&15;
        float sum=0.f, sumsq=0.f;
        for(int i=0;i<16;i++){ float v = xs[g][il*16+i]; sum += v; sumsq += v*v; }
        #pragma unroll
        for(int m=1;m<16;m<<=1){ sum += __shfl_xor(sum,m); sumsq += __shfl_xor(sumsq,m); }
        float mu   = sum*(1.f/256.f);
        float var  = sumsq*(1.f/256.f) - mu*mu;
        float rstd = rsqrtf(var + 1e-5f);
        for(int i=0;i<16;i++){
            int c = il*16+i;
            xs[g][c] = (xs[g][c]-mu)*rstd*nw[c] + nb[c];
        }
        __syncthreads();
        for(int i=0;i<16;i++){
            int idx = i*256+t; int j = idx>>8, c = idx&255;
            Xb[(size_t)(tok0+j)*DMODEL + c] = f2bf(xs[j][c]);
        }
    } else if(bx < 256 + NPAD2/4){
        int n0 = (bx-256)*4, k = t;
        #pragma unroll
        for(int i=0;i<4;i++){
            int n = n0+i;
            float v = (n < DINPROJ) ? Win[(size_t)k*DINPROJ + n] : 0.f;
            Wti[(size_t)n*DMODEL + k] = f2bf(v);
        }
    } else {
        int n0 = (bx - 256 - NPAD2/4)*4;
        #pragma unroll
        for(int kk=0;kk<2;kk++){
            int k = t + kk*256;
            float rw = rms_w[k];
            #pragma unroll
            for(int i=0;i<4;i++){
                int n = n0+i;
                Wto[(size_t)n*DINNER + k] = f2bf(Wout[(size_t)k*DMODEL + n] * rw);
            }
        }
    }
}

// ---------------- in-proj MFMA GEMM: 64x64 tile, full-K one-shot DMA staging, 1 barrier ----------------
// LDS linear (DMA requirement) + XOR chunk swizzle on BOTH source and read (rule #21):
// LDS chunk (row,off) holds global chunk (row, off^(row&7)) -> 8 rows span all 32 banks on read.
__global__ __launch_bounds__(256) void k_gemm_in(
        const unsigned short* __restrict__ A, const unsigned short* __restrict__ Bt,
        unsigned short* __restrict__ zxb){
    __shared__ __align__(16) unsigned short As[64*256];
    __shared__ __align__(16) unsigned short Bs[64*256];
    int t = threadIdx.x;
    int lane = t & 63, w = t >> 6;
    int lanelow = lane & 15, quad = lane >> 4;
    int tok0 = blockIdx.x * 64;
    int n0   = blockIdx.y * 64;
    int rw = (w & 1) * 32, cw = (w >> 1) * 32;
    #pragma unroll
    for(int k=0;k<8;k++){
        int u = t + k*256;
        int row = u >> 5, off = u & 31;
        int soff = off ^ (row & 7);
        gload_lds16(A  + (size_t)(tok0+row)*DMODEL + soff*8, &As[(w*64 + k*256)*8]);
        gload_lds16(Bt + (size_t)(n0 +row)*DMODEL + soff*8, &Bs[(w*64 + k*256)*8]);
    }
    __syncthreads();
    v4f acc[2][2];
    #pragma unroll
    for(int mi=0;mi<2;mi++)
        #pragma unroll
        for(int ni=0;ni<2;ni++)
            acc[mi][ni] = (v4f){0.f,0.f,0.f,0.f};
    #pragma unroll
    for(int k0=0;k0<8;k0++){
        v8s a[2], b[2];
        #pragma unroll
        for(int mi=0;mi<2;mi++){
            int r = rw + mi*16 + lanelow;
            a[mi] = *(const v8s*)&As[r*256 + (((k0*4 + quad) ^ (r & 7)))*8];
        }
        #pragma unroll
        for(int ni=0;ni<2;ni++){
            int r = cw + ni*16 + lanelow;
            b[ni] = *(const v8s*)&Bs[r*256 + (((k0*4 + quad) ^ (r & 7)))*8];
        }
        #pragma unroll
        for(int mi=0;mi<2;mi++)
            #pragma unroll
            for(int ni=0;ni<2;ni++)
                acc[mi][ni] = __builtin_amdgcn_mfma_f32_16x16x32_bf16(a[mi], b[ni], acc[mi][ni], 0,0,0);
    }
    #pragma unroll
    for(int mi=0;mi<2;mi++){
        #pragma unroll
        for(int ni=0;ni<2;ni++){
            int col = n0 + cw + ni*16 + lanelow;
            if(col < DINPROJ){
                #pragma unroll
                for(int r=0;r<4;r++){
                    int row = tok0 + rw + mi*16 + quad*4 + r;
                    zxb[(size_t)row*DINPROJ + col] = f2bf(acc[mi][ni][r]);
                }
            }
        }
    }
}

// ---------------- fused conv + chunk-local SSD via MFMA; double-buffered slabs, 3 blocks/CU ----------------
__global__ __launch_bounds__(256) void k_chunk1(
        const unsigned short* __restrict__ zxb, const float* __restrict__ conv_w, const float* __restrict__ conv_b,
        const float* __restrict__ dt_bias, const float* __restrict__ A_log, const float* __restrict__ D_param,
        unsigned short* __restrict__ yw16, unsigned short* __restrict__ contrib16,
        float* __restrict__ Larr, float* __restrict__ decayArr, unsigned short* __restrict__ Ccv){
    int blk = blockIdx.x;
    int c = blk & 31, h = (blk>>5)&7, b = blk>>8;
    int t = threadIdx.x;
    int lane = t & 63, w = t >> 6;
    int lanelow = lane & 15, quad = lane >> 4;
    __shared__ __align__(16) unsigned short Cb[64*TS];
    __shared__ __align__(16) unsigned short Bb[64*TS];
    __shared__ __align__(16) unsigned short BtW[64*TS];
    __shared__ __align__(16) unsigned short Xt[64*TS];
    __shared__ __align__(16) unsigned short BufRegion[2*19*RS3]; // 2 raw slabs; Gbuf aliases after conv
    __shared__ float Ls[Q], dts[Q], wch[Q];
    unsigned short* Gbuf = BufRegion;
    int l0 = c*Q;
    int bh = b*NHEADS + h;
    const unsigned short* zbase = zxb + (size_t)(b*SEQLEN + l0)*DINPROJ;

    // ---- stage slab 0 (rows l0-3 .. l0+15) ----
    {
        unsigned short* buf = BufRegion;
        #pragma unroll
        for(int i=0;i<4;i++){
            int u = t + 256*i;
            if(u < 19*48){
                int row = u/48, seg = u - row*48;
                int l = l0 - 3 + row;
                int gcol = (seg<16) ? (DINNER + h*HEADDIM + seg*4) : (2*DINNER + (seg-16)*4);
                ushort4 v;
                if(l >= 0) v = *(const ushort4*)(zxb + ((size_t)b*SEQLEN + l)*DINPROJ + gcol);
                else { v.x=0; v.y=0; v.z=0; v.w=0; }
                *(ushort4*)&buf[row*RS3 + seg*4] = v;
            }
        }
    }
    // ---- dt softplus + cumulative L scan + wch ----
    if(t < Q){
        float v = bf2f(zbase[(size_t)t*DINPROJ + (DINPROJ-NHEADS) + h]) + dt_bias[h];
        float dt = (v > 20.f) ? v : log1pf(__expf(v));
        float A  = -__expf(A_log[h]);
        float ld = dt*A;
        #pragma unroll
        for(int off=1; off<64; off<<=1){
            float u = __shfl_up(ld, off);
            if(lane >= off) ld += u;
        }
        Ls[t] = ld; dts[t] = dt;
        float l63 = __shfl(ld, 63);
        wch[t] = __expf(l63 - ld) * dt;
    }
    __syncthreads();

    unsigned short* CcP = Ccv + ((size_t)b*NCH + c)*4096;
    // ---- pipelined conv: load slab s+1 to regs (early), conv slab s, LDS-write slab s+1 (late) ----
    for(int s=0; s<4; s++){
        unsigned short* cur = BufRegion + (s&1)*(19*RS3);
        unsigned short* nxt = BufRegion + ((s+1)&1)*(19*RS3);
        ushort4 stg[4];
        if(s < 3){
            #pragma unroll
            for(int i=0;i<4;i++){
                int u = t + 256*i;
                if(u < 19*48){
                    int row = u/48, seg = u - row*48;
                    int l = l0 + (s+1)*16 - 3 + row;
                    int gcol = (seg<16) ? (DINNER + h*HEADDIM + seg*4) : (2*DINNER + (seg-16)*4);
                    stg[i] = *(const ushort4*)(zxb + ((size_t)b*SEQLEN + l)*DINPROJ + gcol);
                }
            }
        }
        #pragma unroll
        for(int i=0;i<3;i++){
            int u = t + 256*i;
            int stl = u & 15, grp = u >> 4;
            int st = s*16 + stl;
            int ch = grp*4;
            float xk[4][4];
            #pragma unroll
            for(int k=0;k<4;k++){
                ushort4 v = *(const ushort4*)&cur[(stl+k)*RS3 + ch];
                xk[k][0]=bf2f(v.x); xk[k][1]=bf2f(v.y); xk[k][2]=bf2f(v.z); xk[k][3]=bf2f(v.w);
            }
            float wst = wch[st];
            #pragma unroll
            for(int j=0;j<4;j++){
                int chj = ch+j;
                int cc = (chj<64) ? (h*HEADDIM + chj) : (448 + chj);
                float4 wv = *(const float4*)&conv_w[cc*4];
                float acc = conv_b[cc] + wv.x*xk[0][j] + wv.y*xk[1][j] + wv.z*xk[2][j] + wv.w*xk[3][j];
                float sv = acc/(1.f+__expf(-acc));
                if(chj < 64){
                    Xt[chj*TS + st] = f2bf(sv);
                } else if(chj < 128){
                    int n = chj-64;
                    Bb[st*TS + n]  = f2bf(sv);
                    BtW[n*TS + st] = f2bf(sv*wst);
                } else {
                    int n = chj-128;
                    unsigned short sb16 = f2bf(sv);
                    Cb[st*TS + n] = sb16;
                    if(h==0) CcP[st*64 + n] = sb16;
                }
            }
        }
        if(s < 3){
            #pragma unroll
            for(int i=0;i<4;i++){
                int u = t + 256*i;
                if(u < 19*48){
                    int row = u/48, seg = u - row*48;
                    *(ushort4*)&nxt[row*RS3 + seg*4] = stg[i];
                }
            }
        }
        __syncthreads();
    }
    // conv fully done: raw slabs dead, Gbuf may be written
    v4f g[4];
    #pragma unroll
    for(int nt=0;nt<4;nt++) g[nt] = (v4f){0.f,0.f,0.f,0.f};
    #pragma unroll
    for(int kk=0;kk<2;kk++){
        v8s a = *(const v8s*)&Cb[(w*16+lanelow)*TS + kk*32 + quad*8];
        #pragma unroll
        for(int nt=0;nt<4;nt++){
            v8s bb = *(const v8s*)&Bb[(nt*16+lanelow)*TS + kk*32 + quad*8];
            g[nt] = __builtin_amdgcn_mfma_f32_16x16x32_bf16(a, bb, g[nt], 0,0,0);
        }
    }
    float Lrow[4];
    #pragma unroll
    for(int r=0;r<4;r++) Lrow[r] = Ls[w*16 + quad*4 + r];
    #pragma unroll
    for(int nt=0;nt<4;nt++){
        int col = nt*16 + lanelow;
        float Lc = Ls[col], dtc = dts[col];
        #pragma unroll
        for(int r=0;r<4;r++){
            int rowg = w*16 + quad*4 + r;
            float val = (col <= rowg) ? g[nt][r] * __expf(Lrow[r]-Lc) * dtc : 0.f;
            Gbuf[rowg*TS + col] = f2bf(val);
        }
    }
    __syncthreads();
    v4f ya[4], sa[4];
    #pragma unroll
    for(int nt=0;nt<4;nt++){ ya[nt]=(v4f){0.f,0.f,0.f,0.f}; sa[nt]=(v4f){0.f,0.f,0.f,0.f}; }
    #pragma unroll
    for(int kk=0;kk<2;kk++){
        v8s ag = *(const v8s*)&Gbuf[(w*16+lanelow)*TS + kk*32 + quad*8];
        v8s ax = *(const v8s*)&Xt[(w*16+lanelow)*TS + kk*32 + quad*8];
        #pragma unroll
        for(int nt=0;nt<4;nt++){
            v8s bx = *(const v8s*)&Xt[(nt*16+lanelow)*TS + kk*32 + quad*8];
            v8s bw = *(const v8s*)&BtW[(nt*16+lanelow)*TS + kk*32 + quad*8];
            ya[nt] = __builtin_amdgcn_mfma_f32_16x16x32_bf16(ag, bx, ya[nt], 0,0,0);
            sa[nt] = __builtin_amdgcn_mfma_f32_16x16x32_bf16(ax, bw, sa[nt], 0,0,0);
        }
    }
    float Dp = D_param[h];
    #pragma unroll
    for(int nt=0;nt<4;nt++){
        int col = nt*16 + lanelow;
        #pragma unroll
        for(int r=0;r<4;r++){
            int i = w*16 + quad*4 + r;
            float xval = bf2f(Xt[col*TS + i]);
            yw16[((size_t)b*SEQLEN + l0 + i)*DINNER + h*HEADDIM + col] = f2bf(ya[nt][r] + Dp*xval);
            contrib16[(((size_t)bh*NCH + c)*64 + i)*64 + col] = f2bf(sa[nt][r]);
        }
    }
    if(t < Q) Larr[((size_t)bh*NCH + c)*Q + t] = Ls[t];
    if(t == 0) decayArr[bh*NCH + c] = __expf(Ls[Q-1]);
}

// ---------------- inter-chunk state scan (bf16 in/out, fp32 accumulate) ----------------
__global__ __launch_bounds__(256) void k_chunk2(const unsigned short* __restrict__ contrib16,
                                                const float* __restrict__ decayArr,
                                                unsigned short* __restrict__ Sb){
    int bh = blockIdx.x >> 4;
    int part = blockIdx.x & 15;
    int e = part*256 + threadIdx.x;
    const size_t base = (size_t)bh*NCH*4096 + e;
    float vals[NCH];
    #pragma unroll
    for(int c=0;c<NCH;c++) vals[c] = bf2f(contrib16[base + (size_t)c*4096]);
    float s = 0.f;
    #pragma unroll
    for(int c=0;c<NCH;c++){
        Sb[base + (size_t)c*4096] = f2bf(s);
        s = fmaf(s, decayArr[bh*NCH + c], vals[c]);
    }
}

// ---------------- fused inter-chunk y + gate + RMS + out-proj -> fp32 out ----------------
// latency fixes: batched up-front yw16/zxb loads; register double-buffered Wto in ki-loop
__global__ __launch_bounds__(512) void k_tail(
        const unsigned short* __restrict__ Ccv, const unsigned short* __restrict__ Sb,
        const float* __restrict__ Larr, const unsigned short* __restrict__ yw16,
        const unsigned short* __restrict__ zxb, const unsigned short* __restrict__ Wto,
        float* __restrict__ out){
    int blk = blockIdx.x;
    int q4 = blk & 3, c = (blk>>2) & 31, b = blk >> 7;
    int t = threadIdx.x;
    int h = t >> 6, lane = t & 63;
    int lanelow = lane & 15, quad = lane >> 4;
    int bh = b*NHEADS + h;
    __shared__ __align__(16) unsigned short Gs[16*GS];
    __shared__ float wsum[8][16];
    __shared__ float rstdS[16];
    const unsigned short* Cp = Ccv + ((size_t)b*NCH + c)*4096;
    const unsigned short* Sp = Sb + ((size_t)bh*NCH + c)*4096;
    int row0 = q4*16;
    v8s a0 = *(const v8s*)(Cp + (row0+lanelow)*64 + quad*8);
    v8s a1 = *(const v8s*)(Cp + (row0+lanelow)*64 + 32 + quad*8);
    v8s s[4][2];
    #pragma unroll
    for(int nt=0;nt<4;nt++){
        s[nt][0] = *(const v8s*)(Sp + (nt*16+lanelow)*64 + quad*8);
        s[nt][1] = *(const v8s*)(Sp + (nt*16+lanelow)*64 + 32 + quad*8);
    }
    size_t tok0 = (size_t)b*SEQLEN + c*Q + row0;
    // batched independent loads: all yw16/zxb values + Lp, one latency exposure
    unsigned short ywr[4][4], zr[4][4];
    #pragma unroll
    for(int nt=0;nt<4;nt++){
        int col = h*HEADDIM + nt*16 + lanelow;
        #pragma unroll
        for(int r=0;r<4;r++){
            size_t tok = tok0 + quad*4 + r;
            ywr[nt][r] = yw16[tok*DINNER + col];
            zr[nt][r]  = zxb[tok*DINPROJ + col];
        }
    }
    const float* Lp = Larr + ((size_t)bh*NCH + c)*Q;
    float eL[4];
    #pragma unroll
    for(int r=0;r<4;r++) eL[r] = __expf(Lp[row0 + quad*4 + r]);
    // prefetch first Wto pair (hidden under the reduce barriers below)
    const unsigned short* WtoP = Wto + (size_t)(h*32 + lanelow)*DINNER + quad*8;
    v8s w0 = *(const v8s*)(WtoP);
    v8s w1 = *(const v8s*)(WtoP + (size_t)16*DINNER);
    float sq[4] = {0.f,0.f,0.f,0.f};
    #pragma unroll
    for(int nt=0;nt<4;nt++){
        v4f acc = (v4f){0.f,0.f,0.f,0.f};
        acc = __builtin_amdgcn_mfma_f32_16x16x32_bf16(a0, s[nt][0], acc, 0,0,0);
        acc = __builtin_amdgcn_mfma_f32_16x16x32_bf16(a1, s[nt][1], acc, 0,0,0);
        int col = h*HEADDIM + nt*16 + lanelow;
        #pragma unroll
        for(int r=0;r<4;r++){
            float yv = acc[r]*eL[r] + bf2f(ywr[nt][r]);
            float z  = bf2f(zr[nt][r]);
            float gg = yv * (z/(1.f+__expf(-z)));
            Gs[(quad*4+r)*GS + col] = f2bf(gg);
            sq[r] += gg*gg;
        }
    }
    #pragma unroll
    for(int r=0;r<4;r++){
        float v = sq[r];
        #pragma unroll
        for(int m=1;m<16;m<<=1) v += __shfl_xor(v, m);
        sq[r] = v;
    }
    if(lanelow==0){
        #pragma unroll
        for(int r=0;r<4;r++) wsum[h][quad*4 + r] = sq[r];
    }
    __syncthreads();
    if(t < 16){
        float tot = 0.f;
        #pragma unroll
        for(int hh=0;hh<8;hh++) tot += wsum[hh][t];
        rstdS[t] = rsqrtf(tot*(1.f/512.f) + 1e-5f);
    }
    __syncthreads();
    // out-proj: wave h computes cols [h*32, h*32+32); K=512; Wto double-buffered in regs
    v4f acc2[2];
    #pragma unroll
    for(int nt=0;nt<2;nt++) acc2[nt] = (v4f){0.f,0.f,0.f,0.f};
    #pragma unroll
    for(int ki=0; ki<16; ki++){
        v8s nw0, nw1;
        if(ki < 15){
            nw0 = *(const v8s*)(WtoP + (ki+1)*32);
            nw1 = *(const v8s*)(WtoP + (size_t)16*DINNER + (ki+1)*32);
        }
        v8s a = *(const v8s*)&Gs[lanelow*GS + ki*32 + quad*8];
        acc2[0] = __builtin_amdgcn_mfma_f32_16x16x32_bf16(a, w0, acc2[0], 0,0,0);
        acc2[1] = __builtin_amdgcn_mfma_f32_16x16x32_bf16(a, w1, acc2[1], 0,0,0);
        if(ki < 15){ w0 = nw0; w1 = nw1; }
    }
    float rs[4];
    #pragma unroll
    for(int r=0;r<4;r++) rs[r] = rstdS[quad*4 + r];
    #pragma unroll
    for(int nt=0;nt<2;nt++){
        int col = h*32 + nt*16 + lanelow;
        #pragma unroll
        for(int r=0;r<4;r++)
            out[(tok0 + quad*4 + r)*DMODEL + col] = acc2[nt][r]*rs[r];
    }
}

extern "C" void kernel_launch(void* const* d_in, const int* in_sizes, int n_in,
                              void* d_out, int out_size, void* d_ws, size_t ws_size,
                              hipStream_t stream) {
    const float* hid     = (const float*)d_in[0];
    const float* norm_w  = (const float*)d_in[1];
    const float* norm_b  = (const float*)d_in[2];
    const float* Win     = (const float*)d_in[3];
    const float* conv_w  = (const float*)d_in[4];
    const float* conv_b  = (const float*)d_in[5];
    const float* dt_bias = (const float*)d_in[6];
    const float* A_log   = (const float*)d_in[7];
    const float* D_param = (const float*)d_in[8];
    const float* rms_w   = (const float*)d_in[9];
    const float* Wout    = (const float*)d_in[10];

    unsigned short* contrib16 = (unsigned short*)d_ws;            // 16*32*4096 bf16
    float* Larr    = (float*)(contrib16 + (size_t)16*NCH*4096);   // 32768 f
    float* decayA  = Larr + (size_t)16*NCH*Q;                     // 512 f
    unsigned short* zxb  = (unsigned short*)(decayA + 512);       // 4096*1160
    unsigned short* yw16 = zxb + (size_t)NTOK*DINPROJ;            // 4096*512
    unsigned short* Sb   = yw16 + (size_t)NTOK*DINNER;            // 16*32*4096
    unsigned short* Ccv  = Sb + (size_t)16*NCH*4096;              // 2*32*4096
    unsigned short* Xb   = Ccv + (size_t)BATCH*NCH*4096;          // 4096*256
    unsigned short* Wti  = Xb + (size_t)NTOK*DMODEL;              // 1280*256
    unsigned short* Wto  = Wti + (size_t)NPAD2*DMODEL;            // 256*512

    float* out = (float*)d_out;
    float* res = out + (size_t)NTOK*DMODEL;

    k_prep<<<256 + NPAD2/4 + DMODEL/4, 256, 0, stream>>>(hid, norm_w, norm_b, Win, Wout, rms_w, res, Xb, Wti, Wto);
    k_gemm_in<<<dim3(NTOK/64, NPAD2/64), 256, 0, stream>>>(Xb, Wti, zxb);
    k_chunk1<<<BATCH*NHEADS*NCH, 256, 0, stream>>>(zxb, conv_w, conv_b, dt_bias, A_log, D_param,
                                                   yw16, contrib16, Larr, decayA, Ccv);
    k_chunk2<<<256, 256, 0, stream>>>(contrib16, decayA, Sb);
    k_tail<<<BATCH*NCH*4, 512, 0, stream>>>(Ccv, Sb, Larr, yw16, zxb, Wto, out);
}

// Round 8
// 124.602 us; speedup vs baseline: 1.9754x; 1.0118x over previous
//
#include <hip/hip_runtime.h>
#include <hip/hip_bf16.h>

#define BATCH 2
#define SEQLEN 2048
#define DMODEL 256
#define DINNER 512
#define NHEADS 8
#define HEADDIM 64
#define DSTATE 64
#define CONVDIM 640
#define DINPROJ 1160
#define NTOK (BATCH*SEQLEN)
#define Q 64
#define NCH (SEQLEN/Q)
#define NPAD2 1280     // 10*128, zero-padded transposed W_in
#define TS 72          // chunk1 tile stride: word-stride 36 -> bank step 4, 2-way (free)
#define RS3 196        // conv slab stride
#define GS 536         // tail G stride: word-stride 268 -> bank step 12, 2-way (free)

typedef short v8s __attribute__((ext_vector_type(8)));
typedef float v4f __attribute__((ext_vector_type(4)));

__device__ __forceinline__ unsigned short f2bf(float f){
    __hip_bfloat16 h = __float2bfloat16(f);
    return *reinterpret_cast<unsigned short*>(&h);
}
__device__ __forceinline__ float bf2f(unsigned short u){
    unsigned int x = ((unsigned int)u) << 16;
    return __uint_as_float(x);
}
// async global->LDS DMA, 16B per lane; LDS dest = wave-uniform base + lane*16
__device__ __forceinline__ void gload_lds16(const unsigned short* g, unsigned short* l){
    __builtin_amdgcn_global_load_lds((const __attribute__((address_space(1))) void*)g,
                                     (__attribute__((address_space(3))) void*)l, 16, 0, 0);
}

// ---------------- prep: LayerNorm (+residual) and weight conversion, block-partitioned ----------------
__global__ __launch_bounds__(256) void k_prep(
        const float* __restrict__ hid, const float* __restrict__ nw, const float* __restrict__ nb,
        const float* __restrict__ Win, const float* __restrict__ Wout, const float* __restrict__ rms_w,
        float* __restrict__ res, unsigned short* __restrict__ Xb,
        unsigned short* __restrict__ Wti, unsigned short* __restrict__ Wto){
    int bx = blockIdx.x;
    int t = threadIdx.x;
    if(bx < 256){
        __shared__ float xs[16][DMODEL];
        int tok0 = bx*16;
        for(int i=0;i<16;i++){
            int idx = i*256+t; int j = idx>>8, c = idx&255;
            float v = hid[(size_t)(tok0+j)*DMODEL + c];
            xs[j][c] = v;
            res[(size_t)(tok0+j)*DMODEL + c] = v;
        }
        __syncthreads();
        int g = t>>4, il = t&15;
        float sum=0.f, sumsq=0.f;
        for(int i=0;i<16;i++){ float v = xs[g][il*16+i]; sum += v; sumsq += v*v; }
        #pragma unroll
        for(int m=1;m<16;m<<=1){ sum += __shfl_xor(sum,m); sumsq += __shfl_xor(sumsq,m); }
        float mu   = sum*(1.f/256.f);
        float var  = sumsq*(1.f/256.f) - mu*mu;
        float rstd = rsqrtf(var + 1e-5f);
        for(int i=0;i<16;i++){
            int c = il*16+i;
            xs[g][c] = (xs[g][c]-mu)*rstd*nw[c] + nb[c];
        }
        __syncthreads();
        for(int i=0;i<16;i++){
            int idx = i*256+t; int j = idx>>8, c = idx&255;
            Xb[(size_t)(tok0+j)*DMODEL + c] = f2bf(xs[j][c]);
        }
    } else if(bx < 256 + NPAD2/4){
        int n0 = (bx-256)*4, k = t;
        #pragma unroll
        for(int i=0;i<4;i++){
            int n = n0+i;
            float v = (n < DINPROJ) ? Win[(size_t)k*DINPROJ + n] : 0.f;
            Wti[(size_t)n*DMODEL + k] = f2bf(v);
        }
    } else {
        int n0 = (bx - 256 - NPAD2/4)*4;
        #pragma unroll
        for(int kk=0;kk<2;kk++){
            int k = t + kk*256;
            float rw = rms_w[k];
            #pragma unroll
            for(int i=0;i<4;i++){
                int n = n0+i;
                Wto[(size_t)n*DINNER + k] = f2bf(Wout[(size_t)k*DMODEL + n] * rw);
            }
        }
    }
}

// ---------------- in-proj MFMA GEMM: 64x64 tile, 2-phase K (32KB LDS -> 4 blocks/CU) ----------------
// LDS linear (DMA requirement) + XOR chunk swizzle on BOTH source and read (rule #21):
// per phase: LDS chunk (row,off) holds global chunk (row, off^(row&7)), off in [0,16).
__global__ __launch_bounds__(256) void k_gemm_in(
        const unsigned short* __restrict__ A, const unsigned short* __restrict__ Bt,
        unsigned short* __restrict__ zxb){
    __shared__ __align__(16) unsigned short As[64*128];
    __shared__ __align__(16) unsigned short Bs[64*128];
    int t = threadIdx.x;
    int lane = t & 63, w = t >> 6;
    int lanelow = lane & 15, quad = lane >> 4;
    int tok0 = blockIdx.x * 64;
    int n0   = blockIdx.y * 64;
    int rw = (w & 1) * 32, cw = (w >> 1) * 32;
    v4f acc[2][2];
    #pragma unroll
    for(int mi=0;mi<2;mi++)
        #pragma unroll
        for(int ni=0;ni<2;ni++)
            acc[mi][ni] = (v4f){0.f,0.f,0.f,0.f};
    #pragma unroll
    for(int p=0;p<2;p++){
        if(p) __syncthreads();   // protect LDS reuse between phases
        // stage this phase's K-half: 64 rows x 16 chunks per matrix = 4 iters x 256 thr
        #pragma unroll
        for(int i=0;i<4;i++){
            int u = t + i*256;
            int row = u >> 4, off = u & 15;
            int soff = off ^ (row & 7);
            gload_lds16(A  + (size_t)(tok0+row)*DMODEL + p*128 + soff*8, &As[(i*256 + w*64)*8]);
            gload_lds16(Bt + (size_t)(n0 +row)*DMODEL + p*128 + soff*8, &Bs[(i*256 + w*64)*8]);
        }
        __syncthreads();
        #pragma unroll
        for(int k0=0;k0<4;k0++){
            v8s a[2], b[2];
            #pragma unroll
            for(int mi=0;mi<2;mi++){
                int r = rw + mi*16 + lanelow;
                a[mi] = *(const v8s*)&As[r*128 + (((k0*4 + quad) ^ (r & 7)))*8];
            }
            #pragma unroll
            for(int ni=0;ni<2;ni++){
                int r = cw + ni*16 + lanelow;
                b[ni] = *(const v8s*)&Bs[r*128 + (((k0*4 + quad) ^ (r & 7)))*8];
            }
            #pragma unroll
            for(int mi=0;mi<2;mi++)
                #pragma unroll
                for(int ni=0;ni<2;ni++)
                    acc[mi][ni] = __builtin_amdgcn_mfma_f32_16x16x32_bf16(a[mi], b[ni], acc[mi][ni], 0,0,0);
        }
    }
    #pragma unroll
    for(int mi=0;mi<2;mi++){
        #pragma unroll
        for(int ni=0;ni<2;ni++){
            int col = n0 + cw + ni*16 + lanelow;
            if(col < DINPROJ){
                #pragma unroll
                for(int r=0;r<4;r++){
                    int row = tok0 + rw + mi*16 + quad*4 + r;
                    zxb[(size_t)row*DINPROJ + col] = f2bf(acc[mi][ni][r]);
                }
            }
        }
    }
}

// ---------------- fused conv + chunk-local SSD via MFMA; double-buffered slabs, 3 blocks/CU ----------------
__global__ __launch_bounds__(256) void k_chunk1(
        const unsigned short* __restrict__ zxb, const float* __restrict__ conv_w, const float* __restrict__ conv_b,
        const float* __restrict__ dt_bias, const float* __restrict__ A_log, const float* __restrict__ D_param,
        unsigned short* __restrict__ yw16, unsigned short* __restrict__ contrib16,
        float* __restrict__ Larr, float* __restrict__ decayArr, unsigned short* __restrict__ Ccv){
    int blk = blockIdx.x;
    int c = blk & 31, h = (blk>>5)&7, b = blk>>8;
    int t = threadIdx.x;
    int lane = t & 63, w = t >> 6;
    int lanelow = lane & 15, quad = lane >> 4;
    __shared__ __align__(16) unsigned short Cb[64*TS];
    __shared__ __align__(16) unsigned short Bb[64*TS];
    __shared__ __align__(16) unsigned short BtW[64*TS];
    __shared__ __align__(16) unsigned short Xt[64*TS];
    __shared__ __align__(16) unsigned short BufRegion[2*19*RS3]; // 2 raw slabs; Gbuf aliases after conv
    __shared__ float Ls[Q], dts[Q], wch[Q];
    unsigned short* Gbuf = BufRegion;
    int l0 = c*Q;
    int bh = b*NHEADS + h;
    const unsigned short* zbase = zxb + (size_t)(b*SEQLEN + l0)*DINPROJ;

    // ---- stage slab 0 (rows l0-3 .. l0+15) ----
    {
        unsigned short* buf = BufRegion;
        #pragma unroll
        for(int i=0;i<4;i++){
            int u = t + 256*i;
            if(u < 19*48){
                int row = u/48, seg = u - row*48;
                int l = l0 - 3 + row;
                int gcol = (seg<16) ? (DINNER + h*HEADDIM + seg*4) : (2*DINNER + (seg-16)*4);
                ushort4 v;
                if(l >= 0) v = *(const ushort4*)(zxb + ((size_t)b*SEQLEN + l)*DINPROJ + gcol);
                else { v.x=0; v.y=0; v.z=0; v.w=0; }
                *(ushort4*)&buf[row*RS3 + seg*4] = v;
            }
        }
    }
    // ---- dt softplus + cumulative L scan + wch ----
    if(t < Q){
        float v = bf2f(zbase[(size_t)t*DINPROJ + (DINPROJ-NHEADS) + h]) + dt_bias[h];
        float dt = (v > 20.f) ? v : log1pf(__expf(v));
        float A  = -__expf(A_log[h]);
        float ld = dt*A;
        #pragma unroll
        for(int off=1; off<64; off<<=1){
            float u = __shfl_up(ld, off);
            if(lane >= off) ld += u;
        }
        Ls[t] = ld; dts[t] = dt;
        float l63 = __shfl(ld, 63);
        wch[t] = __expf(l63 - ld) * dt;
    }
    __syncthreads();

    unsigned short* CcP = Ccv + ((size_t)b*NCH + c)*4096;
    // ---- pipelined conv: load slab s+1 to regs (early), conv slab s, LDS-write slab s+1 (late) ----
    for(int s=0; s<4; s++){
        unsigned short* cur = BufRegion + (s&1)*(19*RS3);
        unsigned short* nxt = BufRegion + ((s+1)&1)*(19*RS3);
        ushort4 stg[4];
        if(s < 3){
            #pragma unroll
            for(int i=0;i<4;i++){
                int u = t + 256*i;
                if(u < 19*48){
                    int row = u/48, seg = u - row*48;
                    int l = l0 + (s+1)*16 - 3 + row;
                    int gcol = (seg<16) ? (DINNER + h*HEADDIM + seg*4) : (2*DINNER + (seg-16)*4);
                    stg[i] = *(const ushort4*)(zxb + ((size_t)b*SEQLEN + l)*DINPROJ + gcol);
                }
            }
        }
        #pragma unroll
        for(int i=0;i<3;i++){
            int u = t + 256*i;
            int stl = u & 15, grp = u >> 4;
            int st = s*16 + stl;
            int ch = grp*4;
            float xk[4][4];
            #pragma unroll
            for(int k=0;k<4;k++){
                ushort4 v = *(const ushort4*)&cur[(stl+k)*RS3 + ch];
                xk[k][0]=bf2f(v.x); xk[k][1]=bf2f(v.y); xk[k][2]=bf2f(v.z); xk[k][3]=bf2f(v.w);
            }
            float wst = wch[st];
            #pragma unroll
            for(int j=0;j<4;j++){
                int chj = ch+j;
                int cc = (chj<64) ? (h*HEADDIM + chj) : (448 + chj);
                float4 wv = *(const float4*)&conv_w[cc*4];
                float acc = conv_b[cc] + wv.x*xk[0][j] + wv.y*xk[1][j] + wv.z*xk[2][j] + wv.w*xk[3][j];
                float sv = acc/(1.f+__expf(-acc));
                if(chj < 64){
                    Xt[chj*TS + st] = f2bf(sv);
                } else if(chj < 128){
                    int n = chj-64;
                    Bb[st*TS + n]  = f2bf(sv);
                    BtW[n*TS + st] = f2bf(sv*wst);
                } else {
                    int n = chj-128;
                    unsigned short sb16 = f2bf(sv);
                    Cb[st*TS + n] = sb16;
                    if(h==0) CcP[st*64 + n] = sb16;
                }
            }
        }
        if(s < 3){
            #pragma unroll
            for(int i=0;i<4;i++){
                int u = t + 256*i;
                if(u < 19*48){
                    int row = u/48, seg = u - row*48;
                    *(ushort4*)&nxt[row*RS3 + seg*4] = stg[i];
                }
            }
        }
        __syncthreads();
    }
    // conv fully done: raw slabs dead, Gbuf may be written
    v4f g[4];
    #pragma unroll
    for(int nt=0;nt<4;nt++) g[nt] = (v4f){0.f,0.f,0.f,0.f};
    #pragma unroll
    for(int kk=0;kk<2;kk++){
        v8s a = *(const v8s*)&Cb[(w*16+lanelow)*TS + kk*32 + quad*8];
        #pragma unroll
        for(int nt=0;nt<4;nt++){
            v8s bb = *(const v8s*)&Bb[(nt*16+lanelow)*TS + kk*32 + quad*8];
            g[nt] = __builtin_amdgcn_mfma_f32_16x16x32_bf16(a, bb, g[nt], 0,0,0);
        }
    }
    float Lrow[4];
    #pragma unroll
    for(int r=0;r<4;r++) Lrow[r] = Ls[w*16 + quad*4 + r];
    #pragma unroll
    for(int nt=0;nt<4;nt++){
        int col = nt*16 + lanelow;
        float Lc = Ls[col], dtc = dts[col];
        #pragma unroll
        for(int r=0;r<4;r++){
            int rowg = w*16 + quad*4 + r;
            float val = (col <= rowg) ? g[nt][r] * __expf(Lrow[r]-Lc) * dtc : 0.f;
            Gbuf[rowg*TS + col] = f2bf(val);
        }
    }
    __syncthreads();
    v4f ya[4], sa[4];
    #pragma unroll
    for(int nt=0;nt<4;nt++){ ya[nt]=(v4f){0.f,0.f,0.f,0.f}; sa[nt]=(v4f){0.f,0.f,0.f,0.f}; }
    #pragma unroll
    for(int kk=0;kk<2;kk++){
        v8s ag = *(const v8s*)&Gbuf[(w*16+lanelow)*TS + kk*32 + quad*8];
        v8s ax = *(const v8s*)&Xt[(w*16+lanelow)*TS + kk*32 + quad*8];
        #pragma unroll
        for(int nt=0;nt<4;nt++){
            v8s bx = *(const v8s*)&Xt[(nt*16+lanelow)*TS + kk*32 + quad*8];
            v8s bw = *(const v8s*)&BtW[(nt*16+lanelow)*TS + kk*32 + quad*8];
            ya[nt] = __builtin_amdgcn_mfma_f32_16x16x32_bf16(ag, bx, ya[nt], 0,0,0);
            sa[nt] = __builtin_amdgcn_mfma_f32_16x16x32_bf16(ax, bw, sa[nt], 0,0,0);
        }
    }
    float Dp = D_param[h];
    #pragma unroll
    for(int nt=0;nt<4;nt++){
        int col = nt*16 + lanelow;
        #pragma unroll
        for(int r=0;r<4;r++){
            int i = w*16 + quad*4 + r;
            float xval = bf2f(Xt[col*TS + i]);
            yw16[((size_t)b*SEQLEN + l0 + i)*DINNER + h*HEADDIM + col] = f2bf(ya[nt][r] + Dp*xval);
            contrib16[(((size_t)bh*NCH + c)*64 + i)*64 + col] = f2bf(sa[nt][r]);
        }
    }
    if(t < Q) Larr[((size_t)bh*NCH + c)*Q + t] = Ls[t];
    if(t == 0) decayArr[bh*NCH + c] = __expf(Ls[Q-1]);
}

// ---------------- inter-chunk state scan (bf16 in/out, fp32 accumulate) ----------------
__global__ __launch_bounds__(256) void k_chunk2(const unsigned short* __restrict__ contrib16,
                                                const float* __restrict__ decayArr,
                                                unsigned short* __restrict__ Sb){
    int bh = blockIdx.x >> 4;
    int part = blockIdx.x & 15;
    int e = part*256 + threadIdx.x;
    const size_t base = (size_t)bh*NCH*4096 + e;
    float vals[NCH];
    #pragma unroll
    for(int c=0;c<NCH;c++) vals[c] = bf2f(contrib16[base + (size_t)c*4096]);
    float s = 0.f;
    #pragma unroll
    for(int c=0;c<NCH;c++){
        Sb[base + (size_t)c*4096] = f2bf(s);
        s = fmaf(s, decayArr[bh*NCH + c], vals[c]);
    }
}

// ---------------- fused inter-chunk y + gate + RMS + out-proj -> fp32 out ----------------
__global__ __launch_bounds__(512) void k_tail(
        const unsigned short* __restrict__ Ccv, const unsigned short* __restrict__ Sb,
        const float* __restrict__ Larr, const unsigned short* __restrict__ yw16,
        const unsigned short* __restrict__ zxb, const unsigned short* __restrict__ Wto,
        float* __restrict__ out){
    int blk = blockIdx.x;
    int q4 = blk & 3, c = (blk>>2) & 31, b = blk >> 7;
    int t = threadIdx.x;
    int h = t >> 6, lane = t & 63;
    int lanelow = lane & 15, quad = lane >> 4;
    int bh = b*NHEADS + h;
    __shared__ __align__(16) unsigned short Gs[16*GS];
    __shared__ float wsum[8][16];
    __shared__ float rstdS[16];
    const unsigned short* Cp = Ccv + ((size_t)b*NCH + c)*4096;
    const unsigned short* Sp = Sb + ((size_t)bh*NCH + c)*4096;
    int row0 = q4*16;
    v8s a0 = *(const v8s*)(Cp + (row0+lanelow)*64 + quad*8);
    v8s a1 = *(const v8s*)(Cp + (row0+lanelow)*64 + 32 + quad*8);
    v8s s[4][2];
    #pragma unroll
    for(int nt=0;nt<4;nt++){
        s[nt][0] = *(const v8s*)(Sp + (nt*16+lanelow)*64 + quad*8);
        s[nt][1] = *(const v8s*)(Sp + (nt*16+lanelow)*64 + 32 + quad*8);
    }
    float sq[4] = {0.f,0.f,0.f,0.f};
    const float* Lp = Larr + ((size_t)bh*NCH + c)*Q;
    float eL[4];
    #pragma unroll
    for(int r=0;r<4;r++) eL[r] = __expf(Lp[row0 + quad*4 + r]);
    size_t tok0 = (size_t)b*SEQLEN + c*Q + row0;
    #pragma unroll
    for(int nt=0;nt<4;nt++){
        v4f acc = (v4f){0.f,0.f,0.f,0.f};
        acc = __builtin_amdgcn_mfma_f32_16x16x32_bf16(a0, s[nt][0], acc, 0,0,0);
        acc = __builtin_amdgcn_mfma_f32_16x16x32_bf16(a1, s[nt][1], acc, 0,0,0);
        int col = h*HEADDIM + nt*16 + lanelow;
        #pragma unroll
        for(int r=0;r<4;r++){
            size_t tok = tok0 + quad*4 + r;
            float yv = acc[r]*eL[r] + bf2f(yw16[tok*DINNER + col]);
            float z  = bf2f(zxb[tok*DINPROJ + col]);
            float gg = yv * (z/(1.f+__expf(-z)));
            Gs[(quad*4+r)*GS + col] = f2bf(gg);
            sq[r] += gg*gg;
        }
    }
    #pragma unroll
    for(int r=0;r<4;r++){
        float v = sq[r];
        #pragma unroll
        for(int m=1;m<16;m<<=1) v += __shfl_xor(v, m);
        sq[r] = v;
    }
    if(lanelow==0){
        #pragma unroll
        for(int r=0;r<4;r++) wsum[h][quad*4 + r] = sq[r];
    }
    __syncthreads();
    if(t < 16){
        float tot = 0.f;
        #pragma unroll
        for(int hh=0;hh<8;hh++) tot += wsum[hh][t];
        rstdS[t] = rsqrtf(tot*(1.f/512.f) + 1e-5f);
    }
    __syncthreads();
    // out-proj: wave h computes cols [h*32, h*32+32) for these 16 tokens; K=512
    v4f acc2[2];
    #pragma unroll
    for(int nt=0;nt<2;nt++) acc2[nt] = (v4f){0.f,0.f,0.f,0.f};
    for(int ki=0; ki<16; ki++){
        v8s a = *(const v8s*)&Gs[lanelow*GS + ki*32 + quad*8];
        #pragma unroll
        for(int nt=0;nt<2;nt++){
            v8s bfr = *(const v8s*)(Wto + (size_t)(h*32 + nt*16 + lanelow)*DINNER + ki*32 + quad*8);
            acc2[nt] = __builtin_amdgcn_mfma_f32_16x16x32_bf16(a, bfr, acc2[nt], 0,0,0);
        }
    }
    float rs[4];
    #pragma unroll
    for(int r=0;r<4;r++) rs[r] = rstdS[quad*4 + r];
    #pragma unroll
    for(int nt=0;nt<2;nt++){
        int col = h*32 + nt*16 + lanelow;
        #pragma unroll
        for(int r=0;r<4;r++)
            out[(tok0 + quad*4 + r)*DMODEL + col] = acc2[nt][r]*rs[r];
    }
}

extern "C" void kernel_launch(void* const* d_in, const int* in_sizes, int n_in,
                              void* d_out, int out_size, void* d_ws, size_t ws_size,
                              hipStream_t stream) {
    const float* hid     = (const float*)d_in[0];
    const float* norm_w  = (const float*)d_in[1];
    const float* norm_b  = (const float*)d_in[2];
    const float* Win     = (const float*)d_in[3];
    const float* conv_w  = (const float*)d_in[4];
    const float* conv_b  = (const float*)d_in[5];
    const float* dt_bias = (const float*)d_in[6];
    const float* A_log   = (const float*)d_in[7];
    const float* D_param = (const float*)d_in[8];
    const float* rms_w   = (const float*)d_in[9];
    const float* Wout    = (const float*)d_in[10];

    unsigned short* contrib16 = (unsigned short*)d_ws;            // 16*32*4096 bf16
    float* Larr    = (float*)(contrib16 + (size_t)16*NCH*4096);   // 32768 f
    float* decayA  = Larr + (size_t)16*NCH*Q;                     // 512 f
    unsigned short* zxb  = (unsigned short*)(decayA + 512);       // 4096*1160
    unsigned short* yw16 = zxb + (size_t)NTOK*DINPROJ;            // 4096*512
    unsigned short* Sb   = yw16 + (size_t)NTOK*DINNER;            // 16*32*4096
    unsigned short* Ccv  = Sb + (size_t)16*NCH*4096;              // 2*32*4096
    unsigned short* Xb   = Ccv + (size_t)BATCH*NCH*4096;          // 4096*256
    unsigned short* Wti  = Xb + (size_t)NTOK*DMODEL;              // 1280*256
    unsigned short* Wto  = Wti + (size_t)NPAD2*DMODEL;            // 256*512

    float* out = (float*)d_out;
    float* res = out + (size_t)NTOK*DMODEL;

    k_prep<<<256 + NPAD2/4 + DMODEL/4, 256, 0, stream>>>(hid, norm_w, norm_b, Win, Wout, rms_w, res, Xb, Wti, Wto);
    k_gemm_in<<<dim3(NTOK/64, NPAD2/64), 256, 0, stream>>>(Xb, Wti, zxb);
    k_chunk1<<<BATCH*NHEADS*NCH, 256, 0, stream>>>(zxb, conv_w, conv_b, dt_bias, A_log, D_param,
                                                   yw16, contrib16, Larr, decayA, Ccv);
    k_chunk2<<<256, 256, 0, stream>>>(contrib16, decayA, Sb);
    k_tail<<<BATCH*NCH*4, 512, 0, stream>>>(Ccv, Sb, Larr, yw16, zxb, Wto, out);
}